// Round 7
// baseline (217.963 us; speedup 1.0000x reference)
//
#include <hip/hip_runtime.h>

#define N_ROWS 16384
#define C_COLS 2048
#define TWO_C 4096            // sums(2048) + sqsums(2048) per view
#define N_VIEWS 6
#define MOMENT_F 1.6384f      // N/10000
#define SEGS 256              // segments of 64 rows (2 blocks/CU for TLP)
#define LSEG 64               // rows per segment
#define NCHUNK 8              // segment chunks for K1b parallelism
#define SEG_PER_CHUNK (SEGS / NCHUNK)

// ws layout (main path, NO zero-init required):
//   byte 0     : partCnt [SEGS*V]          per-(seg,view) row counts (6 KB)
//   byte 8192  : cntf    [V]               final per-view counts (k1b blk 0)
//   byte 16384 : part    [SEGS*V*TWO_C]    per-(seg,view) sum/sq slabs (25.2 MB)
//   after part : acc2    [NCHUNK*V*TWO_C]  chunk-reduced slabs (786 KB)

// ---------------------------------------------------------------------------
// K1: 512 blocks = 256 segs x 2 col-halves, 256 thr -> 2 blocks/CU.
// Per-wave structure identical to R5 (proven best): 8-row double-buffered
// prefetch groups, register accumulation (6 views x {sum,sq} x float4),
// wave-uniform readfirstlane 6-way branch. R6 showed deeper per-wave ILP
// regresses; this probes the TLP axis instead — 2 co-resident blocks/CU so
// the SIMD scheduler can hide one wave's waitcnt/store tail under the other.
// ---------------------------------------------------------------------------
__global__ __launch_bounds__(256) void k1_tlp(
    const float* __restrict__ x, const int* __restrict__ views,
    float* __restrict__ part, float* __restrict__ partCnt) {
  const int s = blockIdx.x >> 1;    // segment (0..255)
  const int h = blockIdx.x & 1;     // column half
  const int t = threadIdx.x;
  const int r0 = s * LSEG;

  __shared__ int vls[LSEG];
  if (t < LSEG) vls[t] = views[r0 + t];
  __syncthreads();

  if (h == 0 && t < N_VIEWS) {
    int c = 0;
    for (int i = 0; i < LSEG; ++i) c += (vls[i] == t) ? 1 : 0;
    partCnt[s * N_VIEWS + t] = (float)c;
  }

  // per-view register accumulators (static indexing only)
#define DECLV(i) \
  float4 s##i = {0.f,0.f,0.f,0.f}; float4 q##i = {0.f,0.f,0.f,0.f};
  DECLV(0) DECLV(1) DECLV(2) DECLV(3) DECLV(4) DECLV(5)
#undef DECLV

  // thread t owns cols [h*1024 + 4t .. 4t+3]
  const float* xb = x + (size_t)r0 * C_COLS + h * 1024 + 4 * t;

#define LDR(r) (*(const float4*)(xb + (size_t)(r) * C_COLS))
#define LD8(p, base) \
  p##0 = LDR((base) + 0); p##1 = LDR((base) + 1); \
  p##2 = LDR((base) + 2); p##3 = LDR((base) + 3); \
  p##4 = LDR((base) + 4); p##5 = LDR((base) + 5); \
  p##6 = LDR((base) + 6); p##7 = LDR((base) + 7);
#define ACC1(i, b) { \
    s##i.x += b.x; s##i.y += b.y; s##i.z += b.z; s##i.w += b.w; \
    q##i.x = fmaf(b.x, b.x, q##i.x); q##i.y = fmaf(b.y, b.y, q##i.y); \
    q##i.z = fmaf(b.z, b.z, q##i.z); q##i.w = fmaf(b.w, b.w, q##i.w); }
#define PROC1(b, r) { \
    const int v_ = __builtin_amdgcn_readfirstlane(vls[r]); \
    if      (v_ == 0) { ACC1(0, b) } \
    else if (v_ == 1) { ACC1(1, b) } \
    else if (v_ == 2) { ACC1(2, b) } \
    else if (v_ == 3) { ACC1(3, b) } \
    else if (v_ == 4) { ACC1(4, b) } \
    else              { ACC1(5, b) } }
#define PROC8(p, base) \
  PROC1(p##0, (base) + 0) PROC1(p##1, (base) + 1) \
  PROC1(p##2, (base) + 2) PROC1(p##3, (base) + 3) \
  PROC1(p##4, (base) + 4) PROC1(p##5, (base) + 5) \
  PROC1(p##6, (base) + 6) PROC1(p##7, (base) + 7)

  float4 A0, A1, A2, A3, A4, A5, A6, A7;
  float4 B0, B1, B2, B3, B4, B5, B6, B7;

  LD8(A, 0)
  for (int g = 0; g < 8; g += 2) {      // 8 groups of 8 rows = 64 rows
    LD8(B, (g + 1) * 8)
    PROC8(A, g * 8)
    if (g + 2 < 8) { LD8(A, (g + 2) * 8) }
    PROC8(B, (g + 1) * 8)
  }
#undef PROC8
#undef PROC1
#undef ACC1
#undef LD8
#undef LDR

  // write 6 half-slabs straight from registers. Slab (s,v) float4 layout:
  //   f4[0..511]   = sums, cols 0..2047 (h=0 -> f4 0..255, h=1 -> 256..511)
  //   f4[512..1023]= sqs,  cols 0..2047
#define STOREV(i) { \
    float4* dst4 = (float4*)(part + (size_t)(s * N_VIEWS + i) * TWO_C); \
    dst4[h * 256 + t]       = s##i; \
    dst4[512 + h * 256 + t] = q##i; }
  STOREV(0) STOREV(1) STOREV(2) STOREV(3) STOREV(4) STOREV(5)
#undef STOREV
}

// ---------------------------------------------------------------------------
// K1b: reduce 256 segment slabs into 8 chunk slabs. Grid = 192 blocks.
// Thread (chunk, v, c4) sums SEG_PER_CHUNK(=32) float4 partials, plain store
// (no atomics, no zero-init). Block 0 also produces final cntf[6] and
// zeroes out[] (kernel-boundary ordering makes k2's atomicAdd safe).
// ---------------------------------------------------------------------------
__global__ __launch_bounds__(256) void k1b_reduce(
    const float4* __restrict__ part4, float4* __restrict__ acc2_4,
    const float* __restrict__ partCnt, float* __restrict__ cntf,
    float* __restrict__ out, int out_elems) {
  const int u = blockIdx.x * 256 + threadIdx.x;
  const int chunk = u / (N_VIEWS * 1024);
  const int o = u % (N_VIEWS * 1024);
  const int v = o >> 10;
  const int c4 = o & 1023;
  float4 s = {0.f, 0.f, 0.f, 0.f};
  const int segBase = chunk * SEG_PER_CHUNK;
#pragma unroll 8
  for (int i = 0; i < SEG_PER_CHUNK; ++i) {
    float4 p = part4[(size_t)((segBase + i) * N_VIEWS + v) * 1024 + c4];
    s.x += p.x; s.y += p.y; s.z += p.z; s.w += p.w;
  }
  acc2_4[(size_t)(chunk * N_VIEWS + v) * 1024 + c4] = s;

  if (blockIdx.x == 0) {
    if (threadIdx.x < N_VIEWS) {
      float cs = 0.f;
#pragma unroll 8
      for (int i = 0; i < SEGS; ++i) cs += partCnt[i * N_VIEWS + threadIdx.x];
      cntf[threadIdx.x] = cs;
    }
    for (int i = threadIdx.x; i < out_elems; i += 256) out[i] = 0.f;
  }
}

// ---------------------------------------------------------------------------
// K2: 8 blocks x 256 thr, one column per thread. Sums 8 chunk slabs,
// finishes means/stds/new-centers/loss, atomicAdd into out (zeroed by k1b
// block 0). [R4-verified]
// ---------------------------------------------------------------------------
__global__ __launch_bounds__(256) void k2_finish(
    const float* __restrict__ acc2, const float* __restrict__ cntf,
    const float* __restrict__ cmean, const float* __restrict__ cstd,
    float* __restrict__ out) {
  const int c = blockIdx.x * 256 + threadIdx.x;

  float cnt[N_VIEWS];
  float nvalid = 0.f;
#pragma unroll
  for (int v = 0; v < N_VIEWS; ++v) {
    cnt[v] = cntf[v];
    nvalid += (cnt[v] > 1.5f) ? 1.f : 0.f;
  }

  float mean[N_VIEWS], sd[N_VIEWS];
  float nm = 0.f, ns = 0.f;
#pragma unroll
  for (int v = 0; v < N_VIEWS; ++v) {
    float su = 0.f, sq = 0.f;
#pragma unroll
    for (int k = 0; k < NCHUNK; ++k) {
      const float* base = acc2 + (size_t)(k * N_VIEWS + v) * TWO_C;
      su += base[c];
      sq += base[2048 + c];
    }
    float n = fmaxf(cnt[v], 1.f);
    float mu = su / n;
    float var = (sq - cnt[v] * mu * mu) / fmaxf(cnt[v] - 1.f, 1.f);
    float sdv = sqrtf(fmaxf(var, 0.f));
    mean[v] = mu;
    sd[v] = sdv;
    if (cnt[v] > 1.5f) { nm += mu; ns += sdv; }
  }
  nm /= nvalid;
  ns /= nvalid;
  const float cm = cmean[c] * (1.f - MOMENT_F) + nm * MOMENT_F;
  const float cs = cstd[c]  * (1.f - MOMENT_F) + ns * MOMENT_F;

  float contrib = 0.f;
#pragma unroll
  for (int v = 0; v < N_VIEWS; ++v) {
    if (cnt[v] > 1.5f) {
      float d1 = mean[v] - cm;
      float d2 = sd[v] - cs;
      contrib = fmaf(d1, d1, contrib);
      contrib = fmaf(d2, d2, contrib);
    }
  }
  contrib /= (2.f * nvalid);

  for (int o = 32; o > 0; o >>= 1) contrib += __shfl_down(contrib, o, 64);
  __shared__ float wsum[4];
  const int lane = threadIdx.x & 63;
  const int w = threadIdx.x >> 6;
  if (lane == 0) wsum[w] = contrib;
  __syncthreads();
  if (threadIdx.x == 0)
    atomicAdd(out, wsum[0] + wsum[1] + wsum[2] + wsum[3]);
}

// ---------------------------------------------------------------------------
// Fallback path (ws too small): contended-atomic accumulation + memsets.
// ---------------------------------------------------------------------------
__global__ __launch_bounds__(256) void k1_segstats_atomic(
    const float* __restrict__ x, const int* __restrict__ views,
    float* __restrict__ acc, float* __restrict__ counts, int L) {
  const int s = blockIdx.x / N_VIEWS;
  const int v = blockIdx.x % N_VIEWS;
  const int r0 = s * L;
  const int len = min(L, N_ROWS - r0);
  __shared__ int lds_list[256];
  __shared__ int lds_cnt;
  if (threadIdx.x == 0) lds_cnt = 0;
  __syncthreads();
  for (int i = threadIdx.x; i < len; i += 256)
    if (views[r0 + i] == v) lds_list[atomicAdd(&lds_cnt, 1)] = r0 + i;
  __syncthreads();
  const int m = lds_cnt;
  const int t = threadIdx.x;
  float4 sA = {0,0,0,0}, sB = {0,0,0,0}, qA = {0,0,0,0}, qB = {0,0,0,0};
  for (int j = 0; j < m; ++j) {
    const float4* p = (const float4*)(x + (size_t)lds_list[j] * C_COLS);
    float4 a = p[t], b = p[t+256];
    sA.x += a.x; sA.y += a.y; sA.z += a.z; sA.w += a.w;
    sB.x += b.x; sB.y += b.y; sB.z += b.z; sB.w += b.w;
    qA.x = fmaf(a.x,a.x,qA.x); qA.y = fmaf(a.y,a.y,qA.y);
    qA.z = fmaf(a.z,a.z,qA.z); qA.w = fmaf(a.w,a.w,qA.w);
    qB.x = fmaf(b.x,b.x,qB.x); qB.y = fmaf(b.y,b.y,qB.y);
    qB.z = fmaf(b.z,b.z,qB.z); qB.w = fmaf(b.w,b.w,qB.w);
  }
  float* base = acc + v * TWO_C;
  const int cA = 4 * t, cB = 1024 + 4 * t;
  atomicAdd(base+cA+0,sA.x); atomicAdd(base+cA+1,sA.y);
  atomicAdd(base+cA+2,sA.z); atomicAdd(base+cA+3,sA.w);
  atomicAdd(base+cB+0,sB.x); atomicAdd(base+cB+1,sB.y);
  atomicAdd(base+cB+2,sB.z); atomicAdd(base+cB+3,sB.w);
  atomicAdd(base+2048+cA+0,qA.x); atomicAdd(base+2048+cA+1,qA.y);
  atomicAdd(base+2048+cA+2,qA.z); atomicAdd(base+2048+cA+3,qA.w);
  atomicAdd(base+2048+cB+0,qB.x); atomicAdd(base+2048+cB+1,qB.y);
  atomicAdd(base+2048+cB+2,qB.z); atomicAdd(base+2048+cB+3,qB.w);
  if (t == 0) atomicAdd(&counts[v], (float)m);
}

__global__ __launch_bounds__(256) void k2_finish_atomic(
    const float* __restrict__ acc, const float* __restrict__ counts,
    const float* __restrict__ cmean, const float* __restrict__ cstd,
    float* __restrict__ out) {
  const int c = blockIdx.x * 256 + threadIdx.x;
  float cnt[N_VIEWS];
  float nvalid = 0.f;
#pragma unroll
  for (int v = 0; v < N_VIEWS; ++v) {
    cnt[v] = counts[v];
    nvalid += (cnt[v] > 1.5f) ? 1.f : 0.f;
  }
  float mean[N_VIEWS], sd[N_VIEWS];
  float nm = 0.f, ns = 0.f;
#pragma unroll
  for (int v = 0; v < N_VIEWS; ++v) {
    float su = acc[v * TWO_C + c];
    float sq = acc[v * TWO_C + 2048 + c];
    float n = fmaxf(cnt[v], 1.f);
    float mu = su / n;
    float var = (sq - cnt[v] * mu * mu) / fmaxf(cnt[v] - 1.f, 1.f);
    float sdv = sqrtf(fmaxf(var, 0.f));
    mean[v] = mu;
    sd[v] = sdv;
    if (cnt[v] > 1.5f) { nm += mu; ns += sdv; }
  }
  nm /= nvalid;
  ns /= nvalid;
  const float cm = cmean[c] * (1.f - MOMENT_F) + nm * MOMENT_F;
  const float cs = cstd[c]  * (1.f - MOMENT_F) + ns * MOMENT_F;
  float contrib = 0.f;
#pragma unroll
  for (int v = 0; v < N_VIEWS; ++v) {
    if (cnt[v] > 1.5f) {
      float d1 = mean[v] - cm;
      float d2 = sd[v] - cs;
      contrib += d1 * d1 + d2 * d2;
    }
  }
  contrib /= (2.f * nvalid);
  for (int o = 32; o > 0; o >>= 1) contrib += __shfl_down(contrib, o, 64);
  __shared__ float wsum[4];
  const int lane = threadIdx.x & 63;
  const int w = threadIdx.x >> 6;
  if (lane == 0) wsum[w] = contrib;
  __syncthreads();
  if (threadIdx.x == 0)
    atomicAdd(out, wsum[0] + wsum[1] + wsum[2] + wsum[3]);
}

extern "C" void kernel_launch(void* const* d_in, const int* in_sizes, int n_in,
                              void* d_out, int out_size, void* d_ws, size_t ws_size,
                              hipStream_t stream) {
  (void)in_sizes; (void)n_in;
  const float* x     = (const float*)d_in[0];
  const float* cmean = (const float*)d_in[1];
  const float* cstd  = (const float*)d_in[2];
  const int*   views = (const int*)d_in[3];
  float* out = (float*)d_out;

  float* partCnt = (float*)d_ws;
  float* cntf    = (float*)((char*)d_ws + 8192);
  float* part    = (float*)((char*)d_ws + 16384);
  float* acc2    = part + (size_t)SEGS * N_VIEWS * TWO_C;
  const size_t need = 16384 +
      ((size_t)SEGS * N_VIEWS * TWO_C + (size_t)NCHUNK * N_VIEWS * TWO_C) *
          sizeof(float);  // ~26 MB

  if (ws_size >= need) {
    // 3-node graph, no memsets, 2-blocks/CU balanced k1, 8-block k2.
    k1_tlp<<<SEGS * 2, 256, 0, stream>>>(x, views, part, partCnt);
    k1b_reduce<<<NCHUNK * N_VIEWS * 1024 / 256, 256, 0, stream>>>(
        (const float4*)part, (float4*)acc2, partCnt, cntf, out, out_size);
    k2_finish<<<C_COLS / 256, 256, 0, stream>>>(acc2, cntf, cmean, cstd, out);
  } else {
    float* counts = (float*)d_ws;
    float* acc    = (float*)((char*)d_ws + 256);
    hipMemsetAsync(d_ws, 0, 256 + (size_t)N_VIEWS * TWO_C * sizeof(float), stream);
    hipMemsetAsync(d_out, 0, (size_t)out_size * sizeof(float), stream);
    const int L = N_ROWS / 128;
    k1_segstats_atomic<<<N_VIEWS * 128, 256, 0, stream>>>(x, views, acc, counts, L);
    k2_finish_atomic<<<C_COLS / 256, 256, 0, stream>>>(acc, counts, cmean, cstd, out);
  }
}

// Round 8
// 205.666 us; speedup vs baseline: 1.0598x; 1.0598x over previous
//
#include <hip/hip_runtime.h>

#define N_ROWS 16384
#define C_COLS 2048
#define TWO_C 4096            // sums(2048) + sqsums(2048) per view
#define N_VIEWS 6
#define MOMENT_F 1.6384f      // N/10000
#define SEGS 128              // segments of 128 rows
#define LSEG 128              // rows per segment
#define NCHUNK 8              // segment chunks for K1b parallelism
#define SEG_PER_CHUNK (SEGS / NCHUNK)

// ws layout (main path, NO zero-init required):
//   byte 0    : partCnt [SEGS*V]          per-(seg,view) row counts
//   byte 4096 : cntf    [V]               final per-view counts (k1b blk 0)
//   byte 8192 : part    [SEGS*V*TWO_C]    per-(seg,view) sum/sq slabs (12.6 MB)
//   after part: acc2    [NCHUNK*V*TWO_C]  chunk-reduced slabs (786 KB)

// ---------------------------------------------------------------------------
// K1: 256 blocks = 128 segs x 2 col-halves, 256 thr. PERFECTLY BALANCED:
// every block reads exactly 128 rows x 1024 cols (512 KB), no compaction,
// no per-view branching in the load path. Per-view sum/sq accumulated in
// LDS (48 KB; contiguous b128 RMW, conflict-free). 8-row double-buffered
// prefetch keeps 8 KB/wave in flight. [R4-verified session best — the
// measured optimum on both the ILP axis (16-row regressed, R6) and the
// TLP axis (2 blocks/CU regressed, R7); accumulator mechanism is
// irrelevant (reg-accum R5 identical within noise).]
// ---------------------------------------------------------------------------
__global__ __launch_bounds__(256) void k1_balanced(
    const float* __restrict__ x, const int* __restrict__ views,
    float* __restrict__ part, float* __restrict__ partCnt) {
  const int s = blockIdx.x >> 1;    // segment
  const int h = blockIdx.x & 1;     // column half
  const int t = threadIdx.x;
  const int r0 = s * LSEG;

  __shared__ int vls[LSEG];
  __shared__ float lacc[N_VIEWS * 2 * 1024];  // [v][{sum,sq}][1024 cols of this half]

  if (t < LSEG) vls[t] = views[r0 + t];
  float4* lz = (float4*)lacc;
#pragma unroll
  for (int i = 0; i < N_VIEWS * 2; ++i)       // 12 x 256 f4 = 12288 floats
    lz[i * 256 + t] = (float4){0.f, 0.f, 0.f, 0.f};
  __syncthreads();

  if (h == 0 && t < N_VIEWS) {
    int c = 0;
    for (int i = 0; i < LSEG; ++i) c += (vls[i] == t) ? 1 : 0;
    partCnt[s * N_VIEWS + t] = (float)c;
  }

  // thread t owns cols [h*1024 + 4t .. 4t+3]
  const float* xb = x + (size_t)r0 * C_COLS + h * 1024 + 4 * t;

#define LDR(r) (*(const float4*)(xb + (size_t)(r) * C_COLS))
#define LD8(p, base) \
  p##0 = LDR((base) + 0); p##1 = LDR((base) + 1); \
  p##2 = LDR((base) + 2); p##3 = LDR((base) + 3); \
  p##4 = LDR((base) + 4); p##5 = LDR((base) + 5); \
  p##6 = LDR((base) + 6); p##7 = LDR((base) + 7);
#define PROC1(b, r) { \
    const int v_ = vls[r]; \
    float4* ps_ = (float4*)(lacc + v_ * 2048) + t; \
    float4* pq_ = ps_ + 256; \
    float4 sv_ = *ps_; \
    sv_.x += b.x; sv_.y += b.y; sv_.z += b.z; sv_.w += b.w; \
    *ps_ = sv_; \
    float4 qv_ = *pq_; \
    qv_.x = fmaf(b.x, b.x, qv_.x); qv_.y = fmaf(b.y, b.y, qv_.y); \
    qv_.z = fmaf(b.z, b.z, qv_.z); qv_.w = fmaf(b.w, b.w, qv_.w); \
    *pq_ = qv_; }
#define PROC8(p, base) \
  PROC1(p##0, (base) + 0) PROC1(p##1, (base) + 1) \
  PROC1(p##2, (base) + 2) PROC1(p##3, (base) + 3) \
  PROC1(p##4, (base) + 4) PROC1(p##5, (base) + 5) \
  PROC1(p##6, (base) + 6) PROC1(p##7, (base) + 7)

  float4 A0, A1, A2, A3, A4, A5, A6, A7;
  float4 B0, B1, B2, B3, B4, B5, B6, B7;

  LD8(A, 0)
  for (int g = 0; g < 16; g += 2) {     // 16 groups of 8 rows = 128 rows
    LD8(B, (g + 1) * 8)
    PROC8(A, g * 8)
    if (g + 2 < 16) { LD8(A, (g + 2) * 8) }
    PROC8(B, (g + 1) * 8)
  }
#undef PROC8
#undef PROC1
#undef LD8
#undef LDR

  __syncthreads();
  // write 6 half-slabs. Slab (s,v) float4 layout:
  //   f4[0..511]   = sums, cols 0..2047 (h=0 -> f4 0..255, h=1 -> 256..511)
  //   f4[512..1023]= sqs,  cols 0..2047
#pragma unroll
  for (int v = 0; v < N_VIEWS; ++v) {
    float4* dst4 = (float4*)(part + (size_t)(s * N_VIEWS + v) * TWO_C);
    float4* src = (float4*)(lacc + v * 2048);
    dst4[h * 256 + t]       = src[t];        // sums
    dst4[512 + h * 256 + t] = src[256 + t];  // sqs
  }
}

// ---------------------------------------------------------------------------
// K1b: reduce 128 segment slabs into 8 chunk slabs. Grid = 192 blocks.
// Thread (chunk, v, c4) sums SEG_PER_CHUNK float4 partials, plain store
// (no atomics, no zero-init). Block 0 also produces final cntf[6] and
// zeroes out[] (kernel-boundary ordering makes k2's atomicAdd safe).
// [R4-verified]
// ---------------------------------------------------------------------------
__global__ __launch_bounds__(256) void k1b_reduce(
    const float4* __restrict__ part4, float4* __restrict__ acc2_4,
    const float* __restrict__ partCnt, float* __restrict__ cntf,
    float* __restrict__ out, int out_elems) {
  const int u = blockIdx.x * 256 + threadIdx.x;
  const int chunk = u / (N_VIEWS * 1024);
  const int o = u % (N_VIEWS * 1024);
  const int v = o >> 10;
  const int c4 = o & 1023;
  float4 s = {0.f, 0.f, 0.f, 0.f};
  const int segBase = chunk * SEG_PER_CHUNK;
#pragma unroll
  for (int i = 0; i < SEG_PER_CHUNK; ++i) {
    float4 p = part4[(size_t)((segBase + i) * N_VIEWS + v) * 1024 + c4];
    s.x += p.x; s.y += p.y; s.z += p.z; s.w += p.w;
  }
  acc2_4[(size_t)(chunk * N_VIEWS + v) * 1024 + c4] = s;

  if (blockIdx.x == 0) {
    if (threadIdx.x < N_VIEWS) {
      float cs = 0.f;
#pragma unroll 8
      for (int i = 0; i < SEGS; ++i) cs += partCnt[i * N_VIEWS + threadIdx.x];
      cntf[threadIdx.x] = cs;
    }
    for (int i = threadIdx.x; i < out_elems; i += 256) out[i] = 0.f;
  }
}

// ---------------------------------------------------------------------------
// K2: 8 blocks x 256 thr, one column per thread. Sums 8 chunk slabs
// (786 KB spread over 8 CUs ~ 98 KB each), finishes means/stds/new-centers/
// loss, atomicAdd into out (zeroed by k1b block 0). [R4-verified]
// ---------------------------------------------------------------------------
__global__ __launch_bounds__(256) void k2_finish(
    const float* __restrict__ acc2, const float* __restrict__ cntf,
    const float* __restrict__ cmean, const float* __restrict__ cstd,
    float* __restrict__ out) {
  const int c = blockIdx.x * 256 + threadIdx.x;

  float cnt[N_VIEWS];
  float nvalid = 0.f;
#pragma unroll
  for (int v = 0; v < N_VIEWS; ++v) {
    cnt[v] = cntf[v];
    nvalid += (cnt[v] > 1.5f) ? 1.f : 0.f;
  }

  float mean[N_VIEWS], sd[N_VIEWS];
  float nm = 0.f, ns = 0.f;
#pragma unroll
  for (int v = 0; v < N_VIEWS; ++v) {
    float su = 0.f, sq = 0.f;
#pragma unroll
    for (int k = 0; k < NCHUNK; ++k) {
      const float* base = acc2 + (size_t)(k * N_VIEWS + v) * TWO_C;
      su += base[c];
      sq += base[2048 + c];
    }
    float n = fmaxf(cnt[v], 1.f);
    float mu = su / n;
    float var = (sq - cnt[v] * mu * mu) / fmaxf(cnt[v] - 1.f, 1.f);
    float sdv = sqrtf(fmaxf(var, 0.f));
    mean[v] = mu;
    sd[v] = sdv;
    if (cnt[v] > 1.5f) { nm += mu; ns += sdv; }
  }
  nm /= nvalid;
  ns /= nvalid;
  const float cm = cmean[c] * (1.f - MOMENT_F) + nm * MOMENT_F;
  const float cs = cstd[c]  * (1.f - MOMENT_F) + ns * MOMENT_F;

  float contrib = 0.f;
#pragma unroll
  for (int v = 0; v < N_VIEWS; ++v) {
    if (cnt[v] > 1.5f) {
      float d1 = mean[v] - cm;
      float d2 = sd[v] - cs;
      contrib = fmaf(d1, d1, contrib);
      contrib = fmaf(d2, d2, contrib);
    }
  }
  contrib /= (2.f * nvalid);

  for (int o = 32; o > 0; o >>= 1) contrib += __shfl_down(contrib, o, 64);
  __shared__ float wsum[4];
  const int lane = threadIdx.x & 63;
  const int w = threadIdx.x >> 6;
  if (lane == 0) wsum[w] = contrib;
  __syncthreads();
  if (threadIdx.x == 0)
    atomicAdd(out, wsum[0] + wsum[1] + wsum[2] + wsum[3]);
}

// ---------------------------------------------------------------------------
// Fallback path (ws too small): contended-atomic accumulation + memsets.
// ---------------------------------------------------------------------------
__global__ __launch_bounds__(256) void k1_segstats_atomic(
    const float* __restrict__ x, const int* __restrict__ views,
    float* __restrict__ acc, float* __restrict__ counts, int L) {
  const int s = blockIdx.x / N_VIEWS;
  const int v = blockIdx.x % N_VIEWS;
  const int r0 = s * L;
  const int len = min(L, N_ROWS - r0);
  __shared__ int lds_list[256];
  __shared__ int lds_cnt;
  if (threadIdx.x == 0) lds_cnt = 0;
  __syncthreads();
  for (int i = threadIdx.x; i < len; i += 256)
    if (views[r0 + i] == v) lds_list[atomicAdd(&lds_cnt, 1)] = r0 + i;
  __syncthreads();
  const int m = lds_cnt;
  const int t = threadIdx.x;
  float4 sA = {0,0,0,0}, sB = {0,0,0,0}, qA = {0,0,0,0}, qB = {0,0,0,0};
  for (int j = 0; j < m; ++j) {
    const float4* p = (const float4*)(x + (size_t)lds_list[j] * C_COLS);
    float4 a = p[t], b = p[t+256];
    sA.x += a.x; sA.y += a.y; sA.z += a.z; sA.w += a.w;
    sB.x += b.x; sB.y += b.y; sB.z += b.z; sB.w += b.w;
    qA.x = fmaf(a.x,a.x,qA.x); qA.y = fmaf(a.y,a.y,qA.y);
    qA.z = fmaf(a.z,a.z,qA.z); qA.w = fmaf(a.w,a.w,qA.w);
    qB.x = fmaf(b.x,b.x,qB.x); qB.y = fmaf(b.y,b.y,qB.y);
    qB.z = fmaf(b.z,b.z,qB.z); qB.w = fmaf(b.w,b.w,qB.w);
  }
  float* base = acc + v * TWO_C;
  const int cA = 4 * t, cB = 1024 + 4 * t;
  atomicAdd(base+cA+0,sA.x); atomicAdd(base+cA+1,sA.y);
  atomicAdd(base+cA+2,sA.z); atomicAdd(base+cA+3,sA.w);
  atomicAdd(base+cB+0,sB.x); atomicAdd(base+cB+1,sB.y);
  atomicAdd(base+cB+2,sB.z); atomicAdd(base+cB+3,sB.w);
  atomicAdd(base+2048+cA+0,qA.x); atomicAdd(base+2048+cA+1,qA.y);
  atomicAdd(base+2048+cA+2,qA.z); atomicAdd(base+2048+cA+3,qA.w);
  atomicAdd(base+2048+cB+0,qB.x); atomicAdd(base+2048+cB+1,qB.y);
  atomicAdd(base+2048+cB+2,qB.z); atomicAdd(base+2048+cB+3,qB.w);
  if (t == 0) atomicAdd(&counts[v], (float)m);
}

__global__ __launch_bounds__(256) void k2_finish_atomic(
    const float* __restrict__ acc, const float* __restrict__ counts,
    const float* __restrict__ cmean, const float* __restrict__ cstd,
    float* __restrict__ out) {
  const int c = blockIdx.x * 256 + threadIdx.x;
  float cnt[N_VIEWS];
  float nvalid = 0.f;
#pragma unroll
  for (int v = 0; v < N_VIEWS; ++v) {
    cnt[v] = counts[v];
    nvalid += (cnt[v] > 1.5f) ? 1.f : 0.f;
  }
  float mean[N_VIEWS], sd[N_VIEWS];
  float nm = 0.f, ns = 0.f;
#pragma unroll
  for (int v = 0; v < N_VIEWS; ++v) {
    float su = acc[v * TWO_C + c];
    float sq = acc[v * TWO_C + 2048 + c];
    float n = fmaxf(cnt[v], 1.f);
    float mu = su / n;
    float var = (sq - cnt[v] * mu * mu) / fmaxf(cnt[v] - 1.f, 1.f);
    float sdv = sqrtf(fmaxf(var, 0.f));
    mean[v] = mu;
    sd[v] = sdv;
    if (cnt[v] > 1.5f) { nm += mu; ns += sdv; }
  }
  nm /= nvalid;
  ns /= nvalid;
  const float cm = cmean[c] * (1.f - MOMENT_F) + nm * MOMENT_F;
  const float cs = cstd[c]  * (1.f - MOMENT_F) + ns * MOMENT_F;
  float contrib = 0.f;
#pragma unroll
  for (int v = 0; v < N_VIEWS; ++v) {
    if (cnt[v] > 1.5f) {
      float d1 = mean[v] - cm;
      float d2 = sd[v] - cs;
      contrib += d1 * d1 + d2 * d2;
    }
  }
  contrib /= (2.f * nvalid);
  for (int o = 32; o > 0; o >>= 1) contrib += __shfl_down(contrib, o, 64);
  __shared__ float wsum[4];
  const int lane = threadIdx.x & 63;
  const int w = threadIdx.x >> 6;
  if (lane == 0) wsum[w] = contrib;
  __syncthreads();
  if (threadIdx.x == 0)
    atomicAdd(out, wsum[0] + wsum[1] + wsum[2] + wsum[3]);
}

extern "C" void kernel_launch(void* const* d_in, const int* in_sizes, int n_in,
                              void* d_out, int out_size, void* d_ws, size_t ws_size,
                              hipStream_t stream) {
  (void)in_sizes; (void)n_in;
  const float* x     = (const float*)d_in[0];
  const float* cmean = (const float*)d_in[1];
  const float* cstd  = (const float*)d_in[2];
  const int*   views = (const int*)d_in[3];
  float* out = (float*)d_out;

  float* partCnt = (float*)d_ws;
  float* cntf    = (float*)((char*)d_ws + 4096);
  float* part    = (float*)((char*)d_ws + 8192);
  float* acc2    = part + (size_t)SEGS * N_VIEWS * TWO_C;
  const size_t need = 8192 +
      ((size_t)SEGS * N_VIEWS * TWO_C + (size_t)NCHUNK * N_VIEWS * TWO_C) *
          sizeof(float);  // ~13.4 MB

  if (ws_size >= need) {
    // 3-node graph, no memsets, balanced k1, 8-block k2.
    k1_balanced<<<SEGS * 2, 256, 0, stream>>>(x, views, part, partCnt);
    k1b_reduce<<<NCHUNK * N_VIEWS * 1024 / 256, 256, 0, stream>>>(
        (const float4*)part, (float4*)acc2, partCnt, cntf, out, out_size);
    k2_finish<<<C_COLS / 256, 256, 0, stream>>>(acc2, cntf, cmean, cstd, out);
  } else {
    float* counts = (float*)d_ws;
    float* acc    = (float*)((char*)d_ws + 256);
    hipMemsetAsync(d_ws, 0, 256 + (size_t)N_VIEWS * TWO_C * sizeof(float), stream);
    hipMemsetAsync(d_out, 0, (size_t)out_size * sizeof(float), stream);
    const int L = N_ROWS / 128;
    k1_segstats_atomic<<<N_VIEWS * 128, 256, 0, stream>>>(x, views, acc, counts, L);
    k2_finish_atomic<<<C_COLS / 256, 256, 0, stream>>>(acc, counts, cmean, cstd, out);
  }
}